// Round 23
// baseline (2055.387 us; speedup 1.0000x reference)
//
#include <hip/hip_runtime.h>
#include <cstdint>
#include <cstddef>

// ============================================================================
// ConditionalRBM sampler — bit-exact resimulation of the JAX reference.
//
// Round-23: R22 (wave-uniform zero-skip) = best 1440us. Remaining accounting:
// 25.6us/phase vs {LDS-with-skip 15.4 + VALU 5.1 + epilogue 2.7} -> ~10us
// unattributed; conflicts flat at 532K (nib-path, not W reads) -> dominant
// residual = 16 barriers/phase (full drain+resync at 16 waves/CU).
// This round: CH 16->32. Barriers/phase 16->8; chunk = full mask word (drops
// half-word shifts); Wbuf 2x32KiB, LDS ~71.5KiB -> still 2 blocks/CU at
// 512 thr = 4 waves/SIMD. (R20's CH=32 regression was its b64 conflicts,
// not chunk size — grafts cleanly onto R22's verified skeleton.)
// Bit-exact: chunk c covers k=32c..32c+31 ascending; same per-output
// single-acc chains; zero-skip identity unchanged; epilogue verbatim.
//
// ASSUMPTION STACK (verified bit-exact in earlier rounds):
//  A1: jax_threefry_partitionable = True:
//      split(key,n)[i] = TF(key,(0,i)); bits32[j] = TF0(key,(0,j)) ^ TF1(key,(0,j))
//  A2: logistic(x) = 1/(1+exp(-x)), IEEE fdiv
//  A3: exp = XLA-CPU vectorized Cephes/Eigen pexp
//  A4: dot = ascending-k single-accumulator fma chain (exact 0/1 products)
//  A5: x = (dot + udot) + bias association
//  Output dtype: int32 0/1 (harness reads d_out as int32).
//  Pack semantics (R12-verified): state word w of a row, bit b = col 32w+b.
// ============================================================================

#pragma clang fp contract(off)

#define BATCH 8192
#define NU 64
#define NF 256   // num_v == num_h == 256
#define RPB 16   // rows per block (chain kernel)
#define TPB 512  // threads per block (chain kernel) = 8 waves
#define CH 32    // k-rows per staged W chunk (= one full 32-bit mask word)
#define NCH (NF / CH)   // 8 chunks per phase
#define RTI 16   // rows per block in k_udot
#define THERM 24
#define NSAMP 8
#define NSTEP (THERM + NSAMP)   // 32 Gibbs steps

// ---------------- Threefry-2x32 (JAX rotation/injection schedule) ----------
__host__ __device__ __forceinline__ void tf2x32(uint32_t k0, uint32_t k1,
                                                uint32_t x0, uint32_t x1,
                                                uint32_t* o0, uint32_t* o1) {
  uint32_t ks2 = k0 ^ k1 ^ 0x1BD11BDAu;
  x0 += k0; x1 += k1;
#define TFR(r) { x0 += x1; x1 = (x1 << (r)) | (x1 >> (32 - (r))); x1 ^= x0; }
  TFR(13) TFR(15) TFR(26) TFR(6)
  x0 += k1;  x1 += ks2 + 1u;
  TFR(17) TFR(29) TFR(16) TFR(24)
  x0 += ks2; x1 += k0 + 2u;
  TFR(13) TFR(15) TFR(26) TFR(6)
  x0 += k0;  x1 += k1 + 3u;
  TFR(17) TFR(29) TFR(16) TFR(24)
  x0 += k1;  x1 += ks2 + 4u;
  TFR(13) TFR(15) TFR(26) TFR(6)
  x0 += ks2; x1 += k0 + 5u;
#undef TFR
  *o0 = x0; *o1 = x1;
}

// ---------------- XLA-CPU expf (Cephes/Eigen polynomial) -------------------
__device__ __forceinline__ float xla_expf(float x) {
  float xc = fminf(x, 88.3762626647950f);
  xc = fmaxf(xc, -88.3762626647949f);
  float fx = floorf(__builtin_fmaf(xc, 1.44269504088896341f, 0.5f));
  float tmp = 0.693359375f * fx;          // separate rounding (contract off)
  float z = -2.12194440e-4f * fx;
  float r = xc - tmp;
  r = r - z;
  z = r * r;
  float y = __builtin_fmaf(r, 1.9875691500e-4f, 1.3981999507e-3f);
  y = __builtin_fmaf(y, r, 8.3334519073e-3f);
  y = __builtin_fmaf(y, r, 4.1665795894e-2f);
  y = __builtin_fmaf(y, r, 1.6666665459e-1f);
  y = __builtin_fmaf(y, r, 5.0000001201e-1f);
  y = __builtin_fmaf(y, z, r);
  y = y + 1.0f;
  int n = (int)fx;
  float p2 = __int_as_float((n + 127) << 23);
  float res = y * p2;
  return fmaxf(res, x);                   // Eigen pexp: pmax(res, original x)
}

__device__ __forceinline__ float sigmoid_ref(float x) {
  float e = xla_expf(-x);                 // negate exact
  return 1.0f / (1.0f + e);               // IEEE fdiv (no fast-math)
}

// bern: partitionable threefry bits -> uniform [0,1) -> (u < p)
__device__ __forceinline__ float bern_sample(uint32_t key0, uint32_t key1,
                                             uint32_t idx, float p) {
  uint32_t b0, b1;
  tf2x32(key0, key1, 0u, idx, &b0, &b1);  // counter = (hi=0, lo=flat_idx)
  uint32_t bits = b0 ^ b1;                // 32-bit path XORs both words
  float u = __uint_as_float((bits >> 9) | 0x3f800000u) - 1.0f;
  return (u < p) ? 1.0f : 0.0f;
}

// async global->LDS, 16 bytes per lane (linear layout: dest = base+lane*16)
__device__ __forceinline__ void gld_lds16(const float* g, float* l) {
  __builtin_amdgcn_global_load_lds(
      (const __attribute__((address_space(1))) void*)g,
      (__attribute__((address_space(3))) void*)l, 16, 0, 0);
}

// ---------------- kernels ---------------------------------------------------
__global__ void k_transpose(const float* __restrict__ Whv,
                            float* __restrict__ WhvT) {
  int j = threadIdx.x;  // hidden
  int k = blockIdx.x;   // visible
  WhvT[k * NF + j] = Whv[j * NF + k];
}

// out[row][j] = sum_k u[row][k] * W[j][k], ascending k (exact products).
__global__ __launch_bounds__(256, 2) void k_udot(const float* __restrict__ U,
                                                 const float* __restrict__ W,
                                                 float* __restrict__ out) {
  __shared__ __align__(16) float Ulds[NU * RTI];  // [k][i], 4 KiB
  const int j = threadIdx.x;
  const int i0 = blockIdx.x * RTI;
  const int si = j & 15;
  const int sg = j >> 4;
  {
    float4 u4 = *(const float4*)(U + (size_t)(i0 + si) * NU + sg * 4);
    Ulds[(sg * 4 + 0) * RTI + si] = u4.x;
    Ulds[(sg * 4 + 1) * RTI + si] = u4.y;
    Ulds[(sg * 4 + 2) * RTI + si] = u4.z;
    Ulds[(sg * 4 + 3) * RTI + si] = u4.w;
  }
  float wreg[NU];
  const float4* wr4 = (const float4*)(W + (size_t)j * NU);
#pragma unroll
  for (int r = 0; r < NU / 4; ++r) {
    float4 t = wr4[r];
    wreg[4 * r + 0] = t.x; wreg[4 * r + 1] = t.y;
    wreg[4 * r + 2] = t.z; wreg[4 * r + 3] = t.w;
  }
  __syncthreads();
  float acc[RTI];
#pragma unroll
  for (int i = 0; i < RTI; ++i) acc[i] = 0.0f;
#pragma unroll
  for (int kk = 0; kk < NU; ++kk) {
    const float w = wreg[kk];
    const float4 s0 = *(const float4*)(&Ulds[kk * RTI + 0]);
    const float4 s1 = *(const float4*)(&Ulds[kk * RTI + 4]);
    const float4 s2 = *(const float4*)(&Ulds[kk * RTI + 8]);
    const float4 s3 = *(const float4*)(&Ulds[kk * RTI + 12]);
    acc[0]  = __builtin_fmaf(s0.x, w, acc[0]);
    acc[1]  = __builtin_fmaf(s0.y, w, acc[1]);
    acc[2]  = __builtin_fmaf(s0.z, w, acc[2]);
    acc[3]  = __builtin_fmaf(s0.w, w, acc[3]);
    acc[4]  = __builtin_fmaf(s1.x, w, acc[4]);
    acc[5]  = __builtin_fmaf(s1.y, w, acc[5]);
    acc[6]  = __builtin_fmaf(s1.z, w, acc[6]);
    acc[7]  = __builtin_fmaf(s1.w, w, acc[7]);
    acc[8]  = __builtin_fmaf(s2.x, w, acc[8]);
    acc[9]  = __builtin_fmaf(s2.y, w, acc[9]);
    acc[10] = __builtin_fmaf(s2.z, w, acc[10]);
    acc[11] = __builtin_fmaf(s2.w, w, acc[11]);
    acc[12] = __builtin_fmaf(s3.x, w, acc[12]);
    acc[13] = __builtin_fmaf(s3.y, w, acc[13]);
    acc[14] = __builtin_fmaf(s3.z, w, acc[14]);
    acc[15] = __builtin_fmaf(s3.w, w, acc[15]);
  }
#pragma unroll
  for (int i = 0; i < RTI; ++i)
    out[(size_t)(i0 + i) * NF + j] = acc[i];   // row-major (coalesced)
}

// Whole Gibbs chain for 16 rows: init + 32 steps (h,v), samples to out.
// 512 threads = 8 waves; wave owns 2 rows (rg = t>>6), lanes cover 256 cols.
__global__ __launch_bounds__(TPB, 4) void k_chain(
    const float* __restrict__ Whv, const float* __restrict__ WhvT,
    const float* __restrict__ uh, const float* __restrict__ uv,
    const float* __restrict__ bh, const float* __restrict__ bv,
    int* __restrict__ out) {
  __shared__ __align__(16) float Wbuf[2][CH * NF];   // 2 x 32 KiB
  __shared__ uint32_t bitsL[2][RPB * 8];             // [0]=v [1]=h, 1 KiB
  __shared__ uint32_t nib[RPB * 64];                 // 4 KiB pack scratch
  __shared__ float biasL[2][NF];                     // [0]=bh [1]=bv, 2 KiB
  __shared__ uint32_t ksL[66];                       // 33 key pairs
  __shared__ uint32_t keysL[NSTEP * 4];              // (kh0,kh1,kv0,kv1)/step

  const int t = threadIdx.x;
  const int rowbase = blockIdx.x * RPB;
  const int rg = t >> 6;         // wave id (0..7) -> rows {2rg, 2rg+1}
  const int cgg = t & 63;        // 64 col-groups x 4 cols
  const int jc = cgg * 4;        // thread's first col

  // per-thread C operands: 2 rows x 4 cols of uh and uv (coalesced loads)
  float4 cuh[2], cuv[2];
#pragma unroll
  for (int ri = 0; ri < 2; ++ri) {
    const int lr = rg * 2 + ri;
    cuh[ri] = *(const float4*)(uh + (size_t)(rowbase + lr) * NF + jc);
    cuv[ri] = *(const float4*)(uv + (size_t)(rowbase + lr) * NF + jc);
  }

  // ---- prologue: biases + key schedule ----
  if (t < NF) {
    biasL[0][t] = bh[t];
    biasL[1][t] = bv[t];
  }
  if (t < 33) tf2x32(0u, 1u, 0u, (uint32_t)t, &ksL[2 * t], &ksL[2 * t + 1]);
  __syncthreads();
  if (t < NSTEP) {
    uint32_t a = ksL[2 * (1 + t)], b2 = ksL[2 * (1 + t) + 1];
    tf2x32(a, b2, 0u, 0u, &keysL[4 * t + 0], &keysL[4 * t + 1]);
    tf2x32(a, b2, 0u, 1u, &keysL[4 * t + 2], &keysL[4 * t + 3]);
  }
  __syncthreads();

  // ---- init: v0 = bern(ks[0], sigmoid(uv + bv)) -> bitsL[0] ----
  {
    const uint32_t k0 = ksL[0], k1 = ksL[1];
#pragma unroll
    for (int ri = 0; ri < 2; ++ri) {
      const int lr = rg * 2 + ri;
      const int row = rowbase + lr;
      const float4 b4 = *(const float4*)(&biasL[1][jc]);
      const uint32_t idx0 = (uint32_t)(row * NF + jc);
      uint32_t nb = 0;
      nb |= (bern_sample(k0, k1, idx0 + 0,
                 sigmoid_ref(cuv[ri].x + b4.x)) != 0.0f ? 1u : 0u);
      nb |= (bern_sample(k0, k1, idx0 + 1,
                 sigmoid_ref(cuv[ri].y + b4.y)) != 0.0f ? 2u : 0u);
      nb |= (bern_sample(k0, k1, idx0 + 2,
                 sigmoid_ref(cuv[ri].z + b4.z)) != 0.0f ? 4u : 0u);
      nb |= (bern_sample(k0, k1, idx0 + 3,
                 sigmoid_ref(cuv[ri].w + b4.w)) != 0.0f ? 8u : 0u);
      nib[lr * 64 + cgg] = nb;
    }
  }
  __syncthreads();
  if (t < 128) {
    const int lr = t >> 3, wo = t & 7;
    const uint32_t* nn = &nib[lr * 64 + wo * 8];
    uint32_t wrd = 0;
#pragma unroll
    for (int g = 0; g < 8; ++g) wrd |= nn[g] << (4 * g);
    bitsL[0][lr * 8 + wo] = wrd;
  }
  __syncthreads();

  // ---- Gibbs chain: 32 steps x (h-phase, v-phase) ----
#pragma unroll 1
  for (int tt = 0; tt < NSTEP; ++tt) {
#pragma unroll 1
    for (int ph = 0; ph < 2; ++ph) {
      const float* M = ph ? Whv : WhvT;          // reduction index = M row
      const uint32_t* sb = bitsL[ph];            // ph=0 reads v, ph=1 reads h
      uint32_t* db = bitsL[ph ^ 1];
      const float* bl = biasL[ph];
      const uint32_t k0 = keysL[4 * tt + 2 * ph + 0];
      const uint32_t k1 = keysL[4 * tt + 2 * ph + 1];
      int* smp = (ph == 1 && tt >= THERM)
                     ? out + (size_t)(tt - THERM) * BATCH * NF
                     : (int*)nullptr;

      float acc[8];                  // acc[ri*4+ci], ri in {0,1}
#pragma unroll
      for (int q = 0; q < 8; ++q) acc[q] = 0.0f;

      // stage chunk 0 (32 KiB): 4 passes x 512 thr x 16B, async, no regs
#pragma unroll
      for (int q = 0; q < 4; ++q)
        gld_lds16(M + (size_t)(q * TPB + t) * 4, &Wbuf[0][(q * TPB + t) * 4]);
      __syncthreads();   // drains vmcnt -> chunk 0 landed

#pragma unroll 1
      for (int c = 0; c < NCH; ++c) {            // chunk c = mask word c
        if (c + 1 < NCH) {                       // prefetch next chunk
          const float* src = M + (size_t)(c + 1) * CH * NF;
          float* dst = Wbuf[(c + 1) & 1];
#pragma unroll
          for (int q = 0; q < 4; ++q)
            gld_lds16(src + (size_t)(q * TPB + t) * 4,
                      &dst[(q * TPB + t) * 4]);
        }
        // wave-uniform mask words -> SGPRs (scalar pipe does the selects)
        const uint32_t wd0 =
            __builtin_amdgcn_readfirstlane(sb[(rg * 2 + 0) * 8 + c]);
        const uint32_t wd1 =
            __builtin_amdgcn_readfirstlane(sb[(rg * 2 + 1) * 8 + c]);
        const uint32_t wdo = wd0 | wd1;          // any-bit mask (scalar)
        const float* wl = &Wbuf[c & 1][jc];
#pragma unroll 1
        for (int kk = 0; kk < CH; ++kk) {        // m = c*32+kk, ascending
          // wave-uniform ZERO-SKIP: both row-bits 0 -> k contributes
          // exactly +/-0 to every acc -> eliding is bit-identical.
          if (wdo & (1u << kk)) {
            const float4 w = *(const float4*)(wl + kk * NF);
            const float s0 = (wd0 & (1u << kk)) ? 1.0f : 0.0f;  // SALU sel
            const float s1 = (wd1 & (1u << kk)) ? 1.0f : 0.0f;
            acc[0] = __builtin_fmaf(s0, w.x, acc[0]);    // exact products
            acc[1] = __builtin_fmaf(s0, w.y, acc[1]);
            acc[2] = __builtin_fmaf(s0, w.z, acc[2]);
            acc[3] = __builtin_fmaf(s0, w.w, acc[3]);
            acc[4] = __builtin_fmaf(s1, w.x, acc[4]);
            acc[5] = __builtin_fmaf(s1, w.y, acc[5]);
            acc[6] = __builtin_fmaf(s1, w.z, acc[6]);
            acc[7] = __builtin_fmaf(s1, w.w, acc[7]);
          }
        }
        __syncthreads();   // chunk c+1 landed; all done reading buf[c&1]
      }

      // epilogue: x = (dot + udot) + bias ; sigmoid ; bern ; pack bits
      const float4 b4 = *(const float4*)(bl + jc);
#pragma unroll
      for (int ri = 0; ri < 2; ++ri) {
        const int lr = rg * 2 + ri;
        const int row = rowbase + lr;
        const float4 c4 = ph ? cuv[ri] : cuh[ri];   // static idx, uniform ph
        const uint32_t idx0 = (uint32_t)(row * NF + jc);
        const float v0 = bern_sample(k0, k1, idx0 + 0,
            sigmoid_ref((acc[ri * 4 + 0] + c4.x) + b4.x));
        const float v1 = bern_sample(k0, k1, idx0 + 1,
            sigmoid_ref((acc[ri * 4 + 1] + c4.y) + b4.y));
        const float v2 = bern_sample(k0, k1, idx0 + 2,
            sigmoid_ref((acc[ri * 4 + 2] + c4.z) + b4.z));
        const float v3 = bern_sample(k0, k1, idx0 + 3,
            sigmoid_ref((acc[ri * 4 + 3] + c4.w) + b4.w));
        nib[lr * 64 + cgg] = (v0 != 0.0f ? 1u : 0u) |
                             (v1 != 0.0f ? 2u : 0u) |
                             (v2 != 0.0f ? 4u : 0u) |
                             (v3 != 0.0f ? 8u : 0u);
        if (smp) {
          int4 o;
          o.x = (v0 != 0.0f) ? 1 : 0;
          o.y = (v1 != 0.0f) ? 1 : 0;
          o.z = (v2 != 0.0f) ? 1 : 0;
          o.w = (v3 != 0.0f) ? 1 : 0;
          *(int4*)(smp + (size_t)row * NF + jc) = o;
        }
      }
      __syncthreads();
      if (t < 128) {                 // assemble 2 words per row
        const int lr = t >> 3, wo = t & 7;
        const uint32_t* nn = &nib[lr * 64 + wo * 8];
        uint32_t wrd = 0;
#pragma unroll
        for (int g = 0; g < 8; ++g) wrd |= nn[g] << (4 * g);
        db[lr * 8 + wo] = wrd;
      }
      __syncthreads();
    }
  }
}

// ---------------- launch ----------------------------------------------------
extern "C" void kernel_launch(void* const* d_in, const int* in_sizes, int n_in,
                              void* d_out, int out_size, void* d_ws, size_t ws_size,
                              hipStream_t stream) {
  const float* u_state = (const float*)d_in[0];  // [8192][64] 0/1 floats
  const float* Wvu     = (const float*)d_in[1];  // [256][64]
  const float* Whu     = (const float*)d_in[2];  // [256][64]
  const float* Whv     = (const float*)d_in[3];  // [256][256]
  const float* bv      = (const float*)d_in[4];  // [256]
  const float* bh      = (const float*)d_in[5];  // [256]
  int* out = (int*)d_out;                        // [8][8192][256] as int32 0/1

  // workspace: WhvT 256KB + uh 8MB + uv 8MB = ~16.8 MB
  float* ws   = (float*)d_ws;
  float* WhvT = ws;                          // 65536 f
  float* uh   = WhvT + NF * NF;              // [8192][256]
  float* uv   = uh + (size_t)BATCH * NF;

  k_transpose<<<NF, NF, 0, stream>>>(Whv, WhvT);
  k_udot<<<BATCH / RTI, NF, 0, stream>>>(u_state, Whu, uh);   // u @ Whu.T
  k_udot<<<BATCH / RTI, NF, 0, stream>>>(u_state, Wvu, uv);   // u @ Wvu.T
  // whole Gibbs chain in ONE launch (row-independent blocks), 8 waves/block
  k_chain<<<BATCH / RPB, TPB, 0, stream>>>(Whv, WhvT, uh, uv, bh, bv, out);

  (void)in_sizes; (void)n_in; (void)out_size; (void)ws_size;
}

// Round 24
// 1815.086 us; speedup vs baseline: 1.1324x; 1.1324x over previous
//
#include <hip/hip_runtime.h>
#include <cstdint>
#include <cstddef>

// ============================================================================
// ConditionalRBM sampler — bit-exact resimulation of the JAX reference.
//
// Round-24: R23 was CONFOUNDED — it changed CH 16->32 AND kk-loop unroll
// full->1. VALUBusy 62.6->48.7 fingerprints the rolled loop (per-k dynamic
// bit-test + s_cbranch + bookkeeping, branch latency exposed) not the chunk
// size. This round de-confounds: CH=32 (8 barriers/phase, full mask word,
// no half-word shifts) with the kk loop FULLY UNROLLED exactly as R22
// (static s_bitcmp per k, scheduler runs scalar tests ahead of VALU).
// LDS 71.5KiB -> 2 blocks/CU, 4 waves/SIMD (R23 confirmed occupancy holds).
// If >=1440us total, barrier theory dead -> R22 final (practical floor).
// Bit-exact: identical to R23's argument (which passed); only a pragma.
//
// ASSUMPTION STACK (verified bit-exact in earlier rounds):
//  A1: jax_threefry_partitionable = True:
//      split(key,n)[i] = TF(key,(0,i)); bits32[j] = TF0(key,(0,j)) ^ TF1(key,(0,j))
//  A2: logistic(x) = 1/(1+exp(-x)), IEEE fdiv
//  A3: exp = XLA-CPU vectorized Cephes/Eigen pexp
//  A4: dot = ascending-k single-accumulator fma chain (exact 0/1 products)
//  A5: x = (dot + udot) + bias association
//  Output dtype: int32 0/1 (harness reads d_out as int32).
//  Pack semantics (R12-verified): state word w of a row, bit b = col 32w+b.
// ============================================================================

#pragma clang fp contract(off)

#define BATCH 8192
#define NU 64
#define NF 256   // num_v == num_h == 256
#define RPB 16   // rows per block (chain kernel)
#define TPB 512  // threads per block (chain kernel) = 8 waves
#define CH 32    // k-rows per staged W chunk (= one full 32-bit mask word)
#define NCH (NF / CH)   // 8 chunks per phase
#define RTI 16   // rows per block in k_udot
#define THERM 24
#define NSAMP 8
#define NSTEP (THERM + NSAMP)   // 32 Gibbs steps

// ---------------- Threefry-2x32 (JAX rotation/injection schedule) ----------
__host__ __device__ __forceinline__ void tf2x32(uint32_t k0, uint32_t k1,
                                                uint32_t x0, uint32_t x1,
                                                uint32_t* o0, uint32_t* o1) {
  uint32_t ks2 = k0 ^ k1 ^ 0x1BD11BDAu;
  x0 += k0; x1 += k1;
#define TFR(r) { x0 += x1; x1 = (x1 << (r)) | (x1 >> (32 - (r))); x1 ^= x0; }
  TFR(13) TFR(15) TFR(26) TFR(6)
  x0 += k1;  x1 += ks2 + 1u;
  TFR(17) TFR(29) TFR(16) TFR(24)
  x0 += ks2; x1 += k0 + 2u;
  TFR(13) TFR(15) TFR(26) TFR(6)
  x0 += k0;  x1 += k1 + 3u;
  TFR(17) TFR(29) TFR(16) TFR(24)
  x0 += k1;  x1 += ks2 + 4u;
  TFR(13) TFR(15) TFR(26) TFR(6)
  x0 += ks2; x1 += k0 + 5u;
#undef TFR
  *o0 = x0; *o1 = x1;
}

// ---------------- XLA-CPU expf (Cephes/Eigen polynomial) -------------------
__device__ __forceinline__ float xla_expf(float x) {
  float xc = fminf(x, 88.3762626647950f);
  xc = fmaxf(xc, -88.3762626647949f);
  float fx = floorf(__builtin_fmaf(xc, 1.44269504088896341f, 0.5f));
  float tmp = 0.693359375f * fx;          // separate rounding (contract off)
  float z = -2.12194440e-4f * fx;
  float r = xc - tmp;
  r = r - z;
  z = r * r;
  float y = __builtin_fmaf(r, 1.9875691500e-4f, 1.3981999507e-3f);
  y = __builtin_fmaf(y, r, 8.3334519073e-3f);
  y = __builtin_fmaf(y, r, 4.1665795894e-2f);
  y = __builtin_fmaf(y, r, 1.6666665459e-1f);
  y = __builtin_fmaf(y, r, 5.0000001201e-1f);
  y = __builtin_fmaf(y, z, r);
  y = y + 1.0f;
  int n = (int)fx;
  float p2 = __int_as_float((n + 127) << 23);
  float res = y * p2;
  return fmaxf(res, x);                   // Eigen pexp: pmax(res, original x)
}

__device__ __forceinline__ float sigmoid_ref(float x) {
  float e = xla_expf(-x);                 // negate exact
  return 1.0f / (1.0f + e);               // IEEE fdiv (no fast-math)
}

// bern: partitionable threefry bits -> uniform [0,1) -> (u < p)
__device__ __forceinline__ float bern_sample(uint32_t key0, uint32_t key1,
                                             uint32_t idx, float p) {
  uint32_t b0, b1;
  tf2x32(key0, key1, 0u, idx, &b0, &b1);  // counter = (hi=0, lo=flat_idx)
  uint32_t bits = b0 ^ b1;                // 32-bit path XORs both words
  float u = __uint_as_float((bits >> 9) | 0x3f800000u) - 1.0f;
  return (u < p) ? 1.0f : 0.0f;
}

// async global->LDS, 16 bytes per lane (linear layout: dest = base+lane*16)
__device__ __forceinline__ void gld_lds16(const float* g, float* l) {
  __builtin_amdgcn_global_load_lds(
      (const __attribute__((address_space(1))) void*)g,
      (__attribute__((address_space(3))) void*)l, 16, 0, 0);
}

// ---------------- kernels ---------------------------------------------------
__global__ void k_transpose(const float* __restrict__ Whv,
                            float* __restrict__ WhvT) {
  int j = threadIdx.x;  // hidden
  int k = blockIdx.x;   // visible
  WhvT[k * NF + j] = Whv[j * NF + k];
}

// out[row][j] = sum_k u[row][k] * W[j][k], ascending k (exact products).
__global__ __launch_bounds__(256, 2) void k_udot(const float* __restrict__ U,
                                                 const float* __restrict__ W,
                                                 float* __restrict__ out) {
  __shared__ __align__(16) float Ulds[NU * RTI];  // [k][i], 4 KiB
  const int j = threadIdx.x;
  const int i0 = blockIdx.x * RTI;
  const int si = j & 15;
  const int sg = j >> 4;
  {
    float4 u4 = *(const float4*)(U + (size_t)(i0 + si) * NU + sg * 4);
    Ulds[(sg * 4 + 0) * RTI + si] = u4.x;
    Ulds[(sg * 4 + 1) * RTI + si] = u4.y;
    Ulds[(sg * 4 + 2) * RTI + si] = u4.z;
    Ulds[(sg * 4 + 3) * RTI + si] = u4.w;
  }
  float wreg[NU];
  const float4* wr4 = (const float4*)(W + (size_t)j * NU);
#pragma unroll
  for (int r = 0; r < NU / 4; ++r) {
    float4 t = wr4[r];
    wreg[4 * r + 0] = t.x; wreg[4 * r + 1] = t.y;
    wreg[4 * r + 2] = t.z; wreg[4 * r + 3] = t.w;
  }
  __syncthreads();
  float acc[RTI];
#pragma unroll
  for (int i = 0; i < RTI; ++i) acc[i] = 0.0f;
#pragma unroll
  for (int kk = 0; kk < NU; ++kk) {
    const float w = wreg[kk];
    const float4 s0 = *(const float4*)(&Ulds[kk * RTI + 0]);
    const float4 s1 = *(const float4*)(&Ulds[kk * RTI + 4]);
    const float4 s2 = *(const float4*)(&Ulds[kk * RTI + 8]);
    const float4 s3 = *(const float4*)(&Ulds[kk * RTI + 12]);
    acc[0]  = __builtin_fmaf(s0.x, w, acc[0]);
    acc[1]  = __builtin_fmaf(s0.y, w, acc[1]);
    acc[2]  = __builtin_fmaf(s0.z, w, acc[2]);
    acc[3]  = __builtin_fmaf(s0.w, w, acc[3]);
    acc[4]  = __builtin_fmaf(s1.x, w, acc[4]);
    acc[5]  = __builtin_fmaf(s1.y, w, acc[5]);
    acc[6]  = __builtin_fmaf(s1.z, w, acc[6]);
    acc[7]  = __builtin_fmaf(s1.w, w, acc[7]);
    acc[8]  = __builtin_fmaf(s2.x, w, acc[8]);
    acc[9]  = __builtin_fmaf(s2.y, w, acc[9]);
    acc[10] = __builtin_fmaf(s2.z, w, acc[10]);
    acc[11] = __builtin_fmaf(s2.w, w, acc[11]);
    acc[12] = __builtin_fmaf(s3.x, w, acc[12]);
    acc[13] = __builtin_fmaf(s3.y, w, acc[13]);
    acc[14] = __builtin_fmaf(s3.z, w, acc[14]);
    acc[15] = __builtin_fmaf(s3.w, w, acc[15]);
  }
#pragma unroll
  for (int i = 0; i < RTI; ++i)
    out[(size_t)(i0 + i) * NF + j] = acc[i];   // row-major (coalesced)
}

// Whole Gibbs chain for 16 rows: init + 32 steps (h,v), samples to out.
// 512 threads = 8 waves; wave owns 2 rows (rg = t>>6), lanes cover 256 cols.
__global__ __launch_bounds__(TPB, 4) void k_chain(
    const float* __restrict__ Whv, const float* __restrict__ WhvT,
    const float* __restrict__ uh, const float* __restrict__ uv,
    const float* __restrict__ bh, const float* __restrict__ bv,
    int* __restrict__ out) {
  __shared__ __align__(16) float Wbuf[2][CH * NF];   // 2 x 32 KiB
  __shared__ uint32_t bitsL[2][RPB * 8];             // [0]=v [1]=h, 1 KiB
  __shared__ uint32_t nib[RPB * 64];                 // 4 KiB pack scratch
  __shared__ float biasL[2][NF];                     // [0]=bh [1]=bv, 2 KiB
  __shared__ uint32_t ksL[66];                       // 33 key pairs
  __shared__ uint32_t keysL[NSTEP * 4];              // (kh0,kh1,kv0,kv1)/step

  const int t = threadIdx.x;
  const int rowbase = blockIdx.x * RPB;
  const int rg = t >> 6;         // wave id (0..7) -> rows {2rg, 2rg+1}
  const int cgg = t & 63;        // 64 col-groups x 4 cols
  const int jc = cgg * 4;        // thread's first col

  // per-thread C operands: 2 rows x 4 cols of uh and uv (coalesced loads)
  float4 cuh[2], cuv[2];
#pragma unroll
  for (int ri = 0; ri < 2; ++ri) {
    const int lr = rg * 2 + ri;
    cuh[ri] = *(const float4*)(uh + (size_t)(rowbase + lr) * NF + jc);
    cuv[ri] = *(const float4*)(uv + (size_t)(rowbase + lr) * NF + jc);
  }

  // ---- prologue: biases + key schedule ----
  if (t < NF) {
    biasL[0][t] = bh[t];
    biasL[1][t] = bv[t];
  }
  if (t < 33) tf2x32(0u, 1u, 0u, (uint32_t)t, &ksL[2 * t], &ksL[2 * t + 1]);
  __syncthreads();
  if (t < NSTEP) {
    uint32_t a = ksL[2 * (1 + t)], b2 = ksL[2 * (1 + t) + 1];
    tf2x32(a, b2, 0u, 0u, &keysL[4 * t + 0], &keysL[4 * t + 1]);
    tf2x32(a, b2, 0u, 1u, &keysL[4 * t + 2], &keysL[4 * t + 3]);
  }
  __syncthreads();

  // ---- init: v0 = bern(ks[0], sigmoid(uv + bv)) -> bitsL[0] ----
  {
    const uint32_t k0 = ksL[0], k1 = ksL[1];
#pragma unroll
    for (int ri = 0; ri < 2; ++ri) {
      const int lr = rg * 2 + ri;
      const int row = rowbase + lr;
      const float4 b4 = *(const float4*)(&biasL[1][jc]);
      const uint32_t idx0 = (uint32_t)(row * NF + jc);
      uint32_t nb = 0;
      nb |= (bern_sample(k0, k1, idx0 + 0,
                 sigmoid_ref(cuv[ri].x + b4.x)) != 0.0f ? 1u : 0u);
      nb |= (bern_sample(k0, k1, idx0 + 1,
                 sigmoid_ref(cuv[ri].y + b4.y)) != 0.0f ? 2u : 0u);
      nb |= (bern_sample(k0, k1, idx0 + 2,
                 sigmoid_ref(cuv[ri].z + b4.z)) != 0.0f ? 4u : 0u);
      nb |= (bern_sample(k0, k1, idx0 + 3,
                 sigmoid_ref(cuv[ri].w + b4.w)) != 0.0f ? 8u : 0u);
      nib[lr * 64 + cgg] = nb;
    }
  }
  __syncthreads();
  if (t < 128) {
    const int lr = t >> 3, wo = t & 7;
    const uint32_t* nn = &nib[lr * 64 + wo * 8];
    uint32_t wrd = 0;
#pragma unroll
    for (int g = 0; g < 8; ++g) wrd |= nn[g] << (4 * g);
    bitsL[0][lr * 8 + wo] = wrd;
  }
  __syncthreads();

  // ---- Gibbs chain: 32 steps x (h-phase, v-phase) ----
#pragma unroll 1
  for (int tt = 0; tt < NSTEP; ++tt) {
#pragma unroll 1
    for (int ph = 0; ph < 2; ++ph) {
      const float* M = ph ? Whv : WhvT;          // reduction index = M row
      const uint32_t* sb = bitsL[ph];            // ph=0 reads v, ph=1 reads h
      uint32_t* db = bitsL[ph ^ 1];
      const float* bl = biasL[ph];
      const uint32_t k0 = keysL[4 * tt + 2 * ph + 0];
      const uint32_t k1 = keysL[4 * tt + 2 * ph + 1];
      int* smp = (ph == 1 && tt >= THERM)
                     ? out + (size_t)(tt - THERM) * BATCH * NF
                     : (int*)nullptr;

      float acc[8];                  // acc[ri*4+ci], ri in {0,1}
#pragma unroll
      for (int q = 0; q < 8; ++q) acc[q] = 0.0f;

      // stage chunk 0 (32 KiB): 4 passes x 512 thr x 16B, async, no regs
#pragma unroll
      for (int q = 0; q < 4; ++q)
        gld_lds16(M + (size_t)(q * TPB + t) * 4, &Wbuf[0][(q * TPB + t) * 4]);
      __syncthreads();   // drains vmcnt -> chunk 0 landed

#pragma unroll 1
      for (int c = 0; c < NCH; ++c) {            // chunk c = mask word c
        if (c + 1 < NCH) {                       // prefetch next chunk
          const float* src = M + (size_t)(c + 1) * CH * NF;
          float* dst = Wbuf[(c + 1) & 1];
#pragma unroll
          for (int q = 0; q < 4; ++q)
            gld_lds16(src + (size_t)(q * TPB + t) * 4,
                      &dst[(q * TPB + t) * 4]);
        }
        // wave-uniform mask words -> SGPRs (scalar pipe does the selects)
        const uint32_t wd0 =
            __builtin_amdgcn_readfirstlane(sb[(rg * 2 + 0) * 8 + c]);
        const uint32_t wd1 =
            __builtin_amdgcn_readfirstlane(sb[(rg * 2 + 1) * 8 + c]);
        const uint32_t wdo = wd0 | wd1;          // any-bit mask (scalar)
        const float* wl = &Wbuf[c & 1][jc];
#pragma unroll
        for (int kk = 0; kk < CH; ++kk) {        // m = c*32+kk, ascending
          // wave-uniform ZERO-SKIP: both row-bits 0 -> k contributes
          // exactly +/-0 to every acc -> eliding is bit-identical.
          if (wdo & (1u << kk)) {
            const float4 w = *(const float4*)(wl + kk * NF);
            const float s0 = (wd0 & (1u << kk)) ? 1.0f : 0.0f;  // SALU sel
            const float s1 = (wd1 & (1u << kk)) ? 1.0f : 0.0f;
            acc[0] = __builtin_fmaf(s0, w.x, acc[0]);    // exact products
            acc[1] = __builtin_fmaf(s0, w.y, acc[1]);
            acc[2] = __builtin_fmaf(s0, w.z, acc[2]);
            acc[3] = __builtin_fmaf(s0, w.w, acc[3]);
            acc[4] = __builtin_fmaf(s1, w.x, acc[4]);
            acc[5] = __builtin_fmaf(s1, w.y, acc[5]);
            acc[6] = __builtin_fmaf(s1, w.z, acc[6]);
            acc[7] = __builtin_fmaf(s1, w.w, acc[7]);
          }
        }
        __syncthreads();   // chunk c+1 landed; all done reading buf[c&1]
      }

      // epilogue: x = (dot + udot) + bias ; sigmoid ; bern ; pack bits
      const float4 b4 = *(const float4*)(bl + jc);
#pragma unroll
      for (int ri = 0; ri < 2; ++ri) {
        const int lr = rg * 2 + ri;
        const int row = rowbase + lr;
        const float4 c4 = ph ? cuv[ri] : cuh[ri];   // static idx, uniform ph
        const uint32_t idx0 = (uint32_t)(row * NF + jc);
        const float v0 = bern_sample(k0, k1, idx0 + 0,
            sigmoid_ref((acc[ri * 4 + 0] + c4.x) + b4.x));
        const float v1 = bern_sample(k0, k1, idx0 + 1,
            sigmoid_ref((acc[ri * 4 + 1] + c4.y) + b4.y));
        const float v2 = bern_sample(k0, k1, idx0 + 2,
            sigmoid_ref((acc[ri * 4 + 2] + c4.z) + b4.z));
        const float v3 = bern_sample(k0, k1, idx0 + 3,
            sigmoid_ref((acc[ri * 4 + 3] + c4.w) + b4.w));
        nib[lr * 64 + cgg] = (v0 != 0.0f ? 1u : 0u) |
                             (v1 != 0.0f ? 2u : 0u) |
                             (v2 != 0.0f ? 4u : 0u) |
                             (v3 != 0.0f ? 8u : 0u);
        if (smp) {
          int4 o;
          o.x = (v0 != 0.0f) ? 1 : 0;
          o.y = (v1 != 0.0f) ? 1 : 0;
          o.z = (v2 != 0.0f) ? 1 : 0;
          o.w = (v3 != 0.0f) ? 1 : 0;
          *(int4*)(smp + (size_t)row * NF + jc) = o;
        }
      }
      __syncthreads();
      if (t < 128) {                 // assemble 2 words per row
        const int lr = t >> 3, wo = t & 7;
        const uint32_t* nn = &nib[lr * 64 + wo * 8];
        uint32_t wrd = 0;
#pragma unroll
        for (int g = 0; g < 8; ++g) wrd |= nn[g] << (4 * g);
        db[lr * 8 + wo] = wrd;
      }
      __syncthreads();
    }
  }
}

// ---------------- launch ----------------------------------------------------
extern "C" void kernel_launch(void* const* d_in, const int* in_sizes, int n_in,
                              void* d_out, int out_size, void* d_ws, size_t ws_size,
                              hipStream_t stream) {
  const float* u_state = (const float*)d_in[0];  // [8192][64] 0/1 floats
  const float* Wvu     = (const float*)d_in[1];  // [256][64]
  const float* Whu     = (const float*)d_in[2];  // [256][64]
  const float* Whv     = (const float*)d_in[3];  // [256][256]
  const float* bv      = (const float*)d_in[4];  // [256]
  const float* bh      = (const float*)d_in[5];  // [256]
  int* out = (int*)d_out;                        // [8][8192][256] as int32 0/1

  // workspace: WhvT 256KB + uh 8MB + uv 8MB = ~16.8 MB
  float* ws   = (float*)d_ws;
  float* WhvT = ws;                          // 65536 f
  float* uh   = WhvT + NF * NF;              // [8192][256]
  float* uv   = uh + (size_t)BATCH * NF;

  k_transpose<<<NF, NF, 0, stream>>>(Whv, WhvT);
  k_udot<<<BATCH / RTI, NF, 0, stream>>>(u_state, Whu, uh);   // u @ Whu.T
  k_udot<<<BATCH / RTI, NF, 0, stream>>>(u_state, Wvu, uv);   // u @ Wvu.T
  // whole Gibbs chain in ONE launch (row-independent blocks), 8 waves/block
  k_chain<<<BATCH / RPB, TPB, 0, stream>>>(Whv, WhvT, uh, uv, bh, bv, out);

  (void)in_sizes; (void)n_in; (void)out_size; (void)ws_size;
}

// Round 25
// 1441.951 us; speedup vs baseline: 1.4254x; 1.2588x over previous
//
#include <hip/hip_runtime.h>
#include <cstdint>
#include <cstddef>

// ============================================================================
// ConditionalRBM sampler — bit-exact resimulation of the JAX reference.
//
// Round-25: REVERT to R22 (best: 1440us). R23 (CH=32, rolled) exposed branch
// latency; R24 (CH=32, unrolled) crossed the if-conversion threshold and
// predicated the zero-skip away (VALUBusy 88%, slower). Five attempts at the
// ~10us/phase barrier residual all regressed; R22 sits at ~91% of its
// refined model (LDS-with-skip 15.4 + VALU 5.1 + epilogue 2.7 = 23.2 vs
// 25.6 measured). This is the practical floor of the structure.
//
// R22 = fused whole-chain kernel + bit-packed state + wave-uniform scalar
// mask selects + wave-uniform zero-skip (CH=16, kk fully unrolled).
//
// ASSUMPTION STACK (verified bit-exact in earlier rounds):
//  A1: jax_threefry_partitionable = True:
//      split(key,n)[i] = TF(key,(0,i)); bits32[j] = TF0(key,(0,j)) ^ TF1(key,(0,j))
//  A2: logistic(x) = 1/(1+exp(-x)), IEEE fdiv
//  A3: exp = XLA-CPU vectorized Cephes/Eigen pexp
//  A4: dot = ascending-k single-accumulator fma chain (exact 0/1 products)
//  A5: x = (dot + udot) + bias association
//  Output dtype: int32 0/1 (harness reads d_out as int32).
//  Pack semantics (R12-verified): state word w of a row, bit b = col 32w+b.
//  Zero-skip identity: acc=fma(0,w,acc) == acc bitwise (acc never -0).
// ============================================================================

#pragma clang fp contract(off)

#define BATCH 8192
#define NU 64
#define NF 256   // num_v == num_h == 256
#define RPB 16   // rows per block (chain kernel)
#define TPB 512  // threads per block (chain kernel) = 8 waves
#define CH 16    // m-rows per staged W chunk
#define NCH (NF / CH)   // 16 chunks per phase
#define RTI 16   // rows per block in k_udot
#define THERM 24
#define NSAMP 8
#define NSTEP (THERM + NSAMP)   // 32 Gibbs steps

// ---------------- Threefry-2x32 (JAX rotation/injection schedule) ----------
__host__ __device__ __forceinline__ void tf2x32(uint32_t k0, uint32_t k1,
                                                uint32_t x0, uint32_t x1,
                                                uint32_t* o0, uint32_t* o1) {
  uint32_t ks2 = k0 ^ k1 ^ 0x1BD11BDAu;
  x0 += k0; x1 += k1;
#define TFR(r) { x0 += x1; x1 = (x1 << (r)) | (x1 >> (32 - (r))); x1 ^= x0; }
  TFR(13) TFR(15) TFR(26) TFR(6)
  x0 += k1;  x1 += ks2 + 1u;
  TFR(17) TFR(29) TFR(16) TFR(24)
  x0 += ks2; x1 += k0 + 2u;
  TFR(13) TFR(15) TFR(26) TFR(6)
  x0 += k0;  x1 += k1 + 3u;
  TFR(17) TFR(29) TFR(16) TFR(24)
  x0 += k1;  x1 += ks2 + 4u;
  TFR(13) TFR(15) TFR(26) TFR(6)
  x0 += ks2; x1 += k0 + 5u;
#undef TFR
  *o0 = x0; *o1 = x1;
}

// ---------------- XLA-CPU expf (Cephes/Eigen polynomial) -------------------
__device__ __forceinline__ float xla_expf(float x) {
  float xc = fminf(x, 88.3762626647950f);
  xc = fmaxf(xc, -88.3762626647949f);
  float fx = floorf(__builtin_fmaf(xc, 1.44269504088896341f, 0.5f));
  float tmp = 0.693359375f * fx;          // separate rounding (contract off)
  float z = -2.12194440e-4f * fx;
  float r = xc - tmp;
  r = r - z;
  z = r * r;
  float y = __builtin_fmaf(r, 1.9875691500e-4f, 1.3981999507e-3f);
  y = __builtin_fmaf(y, r, 8.3334519073e-3f);
  y = __builtin_fmaf(y, r, 4.1665795894e-2f);
  y = __builtin_fmaf(y, r, 1.6666665459e-1f);
  y = __builtin_fmaf(y, r, 5.0000001201e-1f);
  y = __builtin_fmaf(y, z, r);
  y = y + 1.0f;
  int n = (int)fx;
  float p2 = __int_as_float((n + 127) << 23);
  float res = y * p2;
  return fmaxf(res, x);                   // Eigen pexp: pmax(res, original x)
}

__device__ __forceinline__ float sigmoid_ref(float x) {
  float e = xla_expf(-x);                 // negate exact
  return 1.0f / (1.0f + e);               // IEEE fdiv (no fast-math)
}

// bern: partitionable threefry bits -> uniform [0,1) -> (u < p)
__device__ __forceinline__ float bern_sample(uint32_t key0, uint32_t key1,
                                             uint32_t idx, float p) {
  uint32_t b0, b1;
  tf2x32(key0, key1, 0u, idx, &b0, &b1);  // counter = (hi=0, lo=flat_idx)
  uint32_t bits = b0 ^ b1;                // 32-bit path XORs both words
  float u = __uint_as_float((bits >> 9) | 0x3f800000u) - 1.0f;
  return (u < p) ? 1.0f : 0.0f;
}

// async global->LDS, 16 bytes per lane (linear layout: dest = base+lane*16)
__device__ __forceinline__ void gld_lds16(const float* g, float* l) {
  __builtin_amdgcn_global_load_lds(
      (const __attribute__((address_space(1))) void*)g,
      (__attribute__((address_space(3))) void*)l, 16, 0, 0);
}

// ---------------- kernels ---------------------------------------------------
__global__ void k_transpose(const float* __restrict__ Whv,
                            float* __restrict__ WhvT) {
  int j = threadIdx.x;  // hidden
  int k = blockIdx.x;   // visible
  WhvT[k * NF + j] = Whv[j * NF + k];
}

// out[row][j] = sum_k u[row][k] * W[j][k], ascending k (exact products).
__global__ __launch_bounds__(256, 2) void k_udot(const float* __restrict__ U,
                                                 const float* __restrict__ W,
                                                 float* __restrict__ out) {
  __shared__ __align__(16) float Ulds[NU * RTI];  // [k][i], 4 KiB
  const int j = threadIdx.x;
  const int i0 = blockIdx.x * RTI;
  const int si = j & 15;
  const int sg = j >> 4;
  {
    float4 u4 = *(const float4*)(U + (size_t)(i0 + si) * NU + sg * 4);
    Ulds[(sg * 4 + 0) * RTI + si] = u4.x;
    Ulds[(sg * 4 + 1) * RTI + si] = u4.y;
    Ulds[(sg * 4 + 2) * RTI + si] = u4.z;
    Ulds[(sg * 4 + 3) * RTI + si] = u4.w;
  }
  float wreg[NU];
  const float4* wr4 = (const float4*)(W + (size_t)j * NU);
#pragma unroll
  for (int r = 0; r < NU / 4; ++r) {
    float4 t = wr4[r];
    wreg[4 * r + 0] = t.x; wreg[4 * r + 1] = t.y;
    wreg[4 * r + 2] = t.z; wreg[4 * r + 3] = t.w;
  }
  __syncthreads();
  float acc[RTI];
#pragma unroll
  for (int i = 0; i < RTI; ++i) acc[i] = 0.0f;
#pragma unroll
  for (int kk = 0; kk < NU; ++kk) {
    const float w = wreg[kk];
    const float4 s0 = *(const float4*)(&Ulds[kk * RTI + 0]);
    const float4 s1 = *(const float4*)(&Ulds[kk * RTI + 4]);
    const float4 s2 = *(const float4*)(&Ulds[kk * RTI + 8]);
    const float4 s3 = *(const float4*)(&Ulds[kk * RTI + 12]);
    acc[0]  = __builtin_fmaf(s0.x, w, acc[0]);
    acc[1]  = __builtin_fmaf(s0.y, w, acc[1]);
    acc[2]  = __builtin_fmaf(s0.z, w, acc[2]);
    acc[3]  = __builtin_fmaf(s0.w, w, acc[3]);
    acc[4]  = __builtin_fmaf(s1.x, w, acc[4]);
    acc[5]  = __builtin_fmaf(s1.y, w, acc[5]);
    acc[6]  = __builtin_fmaf(s1.z, w, acc[6]);
    acc[7]  = __builtin_fmaf(s1.w, w, acc[7]);
    acc[8]  = __builtin_fmaf(s2.x, w, acc[8]);
    acc[9]  = __builtin_fmaf(s2.y, w, acc[9]);
    acc[10] = __builtin_fmaf(s2.z, w, acc[10]);
    acc[11] = __builtin_fmaf(s2.w, w, acc[11]);
    acc[12] = __builtin_fmaf(s3.x, w, acc[12]);
    acc[13] = __builtin_fmaf(s3.y, w, acc[13]);
    acc[14] = __builtin_fmaf(s3.z, w, acc[14]);
    acc[15] = __builtin_fmaf(s3.w, w, acc[15]);
  }
#pragma unroll
  for (int i = 0; i < RTI; ++i)
    out[(size_t)(i0 + i) * NF + j] = acc[i];   // row-major (coalesced)
}

// Whole Gibbs chain for 16 rows: init + 32 steps (h,v), samples to out.
// 512 threads = 8 waves; wave owns 2 rows (rg = t>>6), lanes cover 256 cols.
__global__ __launch_bounds__(TPB, 4) void k_chain(
    const float* __restrict__ Whv, const float* __restrict__ WhvT,
    const float* __restrict__ uh, const float* __restrict__ uv,
    const float* __restrict__ bh, const float* __restrict__ bv,
    int* __restrict__ out) {
  __shared__ __align__(16) float Wbuf[2][CH * NF];   // 2 x 16 KiB
  __shared__ uint32_t bitsL[2][RPB * 8];             // [0]=v [1]=h, 1 KiB
  __shared__ uint32_t nib[RPB * 64];                 // 4 KiB pack scratch
  __shared__ float biasL[2][NF];                     // [0]=bh [1]=bv, 2 KiB
  __shared__ uint32_t ksL[66];                       // 33 key pairs
  __shared__ uint32_t keysL[NSTEP * 4];              // (kh0,kh1,kv0,kv1)/step

  const int t = threadIdx.x;
  const int rowbase = blockIdx.x * RPB;
  const int rg = t >> 6;         // wave id (0..7) -> rows {2rg, 2rg+1}
  const int cgg = t & 63;        // 64 col-groups x 4 cols
  const int jc = cgg * 4;        // thread's first col

  // per-thread C operands: 2 rows x 4 cols of uh and uv (coalesced loads)
  float4 cuh[2], cuv[2];
#pragma unroll
  for (int ri = 0; ri < 2; ++ri) {
    const int lr = rg * 2 + ri;
    cuh[ri] = *(const float4*)(uh + (size_t)(rowbase + lr) * NF + jc);
    cuv[ri] = *(const float4*)(uv + (size_t)(rowbase + lr) * NF + jc);
  }

  // ---- prologue: biases + key schedule ----
  if (t < NF) {
    biasL[0][t] = bh[t];
    biasL[1][t] = bv[t];
  }
  if (t < 33) tf2x32(0u, 1u, 0u, (uint32_t)t, &ksL[2 * t], &ksL[2 * t + 1]);
  __syncthreads();
  if (t < NSTEP) {
    uint32_t a = ksL[2 * (1 + t)], b2 = ksL[2 * (1 + t) + 1];
    tf2x32(a, b2, 0u, 0u, &keysL[4 * t + 0], &keysL[4 * t + 1]);
    tf2x32(a, b2, 0u, 1u, &keysL[4 * t + 2], &keysL[4 * t + 3]);
  }
  __syncthreads();

  // ---- init: v0 = bern(ks[0], sigmoid(uv + bv)) -> bitsL[0] ----
  {
    const uint32_t k0 = ksL[0], k1 = ksL[1];
#pragma unroll
    for (int ri = 0; ri < 2; ++ri) {
      const int lr = rg * 2 + ri;
      const int row = rowbase + lr;
      const float4 b4 = *(const float4*)(&biasL[1][jc]);
      const uint32_t idx0 = (uint32_t)(row * NF + jc);
      uint32_t nb = 0;
      nb |= (bern_sample(k0, k1, idx0 + 0,
                 sigmoid_ref(cuv[ri].x + b4.x)) != 0.0f ? 1u : 0u);
      nb |= (bern_sample(k0, k1, idx0 + 1,
                 sigmoid_ref(cuv[ri].y + b4.y)) != 0.0f ? 2u : 0u);
      nb |= (bern_sample(k0, k1, idx0 + 2,
                 sigmoid_ref(cuv[ri].z + b4.z)) != 0.0f ? 4u : 0u);
      nb |= (bern_sample(k0, k1, idx0 + 3,
                 sigmoid_ref(cuv[ri].w + b4.w)) != 0.0f ? 8u : 0u);
      nib[lr * 64 + cgg] = nb;
    }
  }
  __syncthreads();
  if (t < 128) {
    const int lr = t >> 3, wo = t & 7;
    const uint32_t* nn = &nib[lr * 64 + wo * 8];
    uint32_t wrd = 0;
#pragma unroll
    for (int g = 0; g < 8; ++g) wrd |= nn[g] << (4 * g);
    bitsL[0][lr * 8 + wo] = wrd;
  }
  __syncthreads();

  // ---- Gibbs chain: 32 steps x (h-phase, v-phase) ----
#pragma unroll 1
  for (int tt = 0; tt < NSTEP; ++tt) {
#pragma unroll 1
    for (int ph = 0; ph < 2; ++ph) {
      const float* M = ph ? Whv : WhvT;          // reduction index = M row
      const uint32_t* sb = bitsL[ph];            // ph=0 reads v, ph=1 reads h
      uint32_t* db = bitsL[ph ^ 1];
      const float* bl = biasL[ph];
      const uint32_t k0 = keysL[4 * tt + 2 * ph + 0];
      const uint32_t k1 = keysL[4 * tt + 2 * ph + 1];
      int* smp = (ph == 1 && tt >= THERM)
                     ? out + (size_t)(tt - THERM) * BATCH * NF
                     : (int*)nullptr;

      float acc[8];                  // acc[ri*4+ci], ri in {0,1}
#pragma unroll
      for (int q = 0; q < 8; ++q) acc[q] = 0.0f;

      // stage chunk 0 (async, no registers): 512 thr x 2 x 16B = 16 KiB
#pragma unroll
      for (int q = 0; q < 2; ++q)
        gld_lds16(M + (size_t)(q * TPB + t) * 4, &Wbuf[0][(q * TPB + t) * 4]);
      __syncthreads();   // drains vmcnt -> chunk 0 landed

#pragma unroll 1
      for (int c = 0; c < NCH; ++c) {
        if (c + 1 < NCH) {                       // prefetch next chunk
          const float* src = M + (size_t)(c + 1) * CH * NF;
          float* dst = Wbuf[(c + 1) & 1];
#pragma unroll
          for (int q = 0; q < 2; ++q)
            gld_lds16(src + (size_t)(q * TPB + t) * 4,
                      &dst[(q * TPB + t) * 4]);
        }
        const int wi = c >> 1;
        const int hs = (c & 1) * 16;             // which half of the word
        // wave-uniform mask words -> SGPRs (scalar pipe does the selects)
        const uint32_t wd0 =
            __builtin_amdgcn_readfirstlane(sb[(rg * 2 + 0) * 8 + wi]) >> hs;
        const uint32_t wd1 =
            __builtin_amdgcn_readfirstlane(sb[(rg * 2 + 1) * 8 + wi]) >> hs;
        const uint32_t wdo = wd0 | wd1;          // any-bit mask (scalar)
        const float* wl = &Wbuf[c & 1][jc];
#pragma unroll
        for (int kk = 0; kk < CH; ++kk) {        // m = c*16+kk, ascending
          // wave-uniform ZERO-SKIP: both row-bits 0 -> k contributes
          // exactly +/-0 to every acc -> eliding is bit-identical.
          if (wdo & (1u << kk)) {
            const float4 w = *(const float4*)(wl + kk * NF);
            const float s0 = (wd0 & (1u << kk)) ? 1.0f : 0.0f;  // SALU sel
            const float s1 = (wd1 & (1u << kk)) ? 1.0f : 0.0f;
            acc[0] = __builtin_fmaf(s0, w.x, acc[0]);    // exact products
            acc[1] = __builtin_fmaf(s0, w.y, acc[1]);
            acc[2] = __builtin_fmaf(s0, w.z, acc[2]);
            acc[3] = __builtin_fmaf(s0, w.w, acc[3]);
            acc[4] = __builtin_fmaf(s1, w.x, acc[4]);
            acc[5] = __builtin_fmaf(s1, w.y, acc[5]);
            acc[6] = __builtin_fmaf(s1, w.z, acc[6]);
            acc[7] = __builtin_fmaf(s1, w.w, acc[7]);
          }
        }
        __syncthreads();   // chunk c+1 landed; all done reading buf[c&1]
      }

      // epilogue: x = (dot + udot) + bias ; sigmoid ; bern ; pack bits
      const float4 b4 = *(const float4*)(bl + jc);
#pragma unroll
      for (int ri = 0; ri < 2; ++ri) {
        const int lr = rg * 2 + ri;
        const int row = rowbase + lr;
        const float4 c4 = ph ? cuv[ri] : cuh[ri];   // static idx, uniform ph
        const uint32_t idx0 = (uint32_t)(row * NF + jc);
        const float v0 = bern_sample(k0, k1, idx0 + 0,
            sigmoid_ref((acc[ri * 4 + 0] + c4.x) + b4.x));
        const float v1 = bern_sample(k0, k1, idx0 + 1,
            sigmoid_ref((acc[ri * 4 + 1] + c4.y) + b4.y));
        const float v2 = bern_sample(k0, k1, idx0 + 2,
            sigmoid_ref((acc[ri * 4 + 2] + c4.z) + b4.z));
        const float v3 = bern_sample(k0, k1, idx0 + 3,
            sigmoid_ref((acc[ri * 4 + 3] + c4.w) + b4.w));
        nib[lr * 64 + cgg] = (v0 != 0.0f ? 1u : 0u) |
                             (v1 != 0.0f ? 2u : 0u) |
                             (v2 != 0.0f ? 4u : 0u) |
                             (v3 != 0.0f ? 8u : 0u);
        if (smp) {
          int4 o;
          o.x = (v0 != 0.0f) ? 1 : 0;
          o.y = (v1 != 0.0f) ? 1 : 0;
          o.z = (v2 != 0.0f) ? 1 : 0;
          o.w = (v3 != 0.0f) ? 1 : 0;
          *(int4*)(smp + (size_t)row * NF + jc) = o;
        }
      }
      __syncthreads();
      if (t < 128) {                 // assemble 2 words per row
        const int lr = t >> 3, wo = t & 7;
        const uint32_t* nn = &nib[lr * 64 + wo * 8];
        uint32_t wrd = 0;
#pragma unroll
        for (int g = 0; g < 8; ++g) wrd |= nn[g] << (4 * g);
        db[lr * 8 + wo] = wrd;
      }
      __syncthreads();
    }
  }
}

// ---------------- launch ----------------------------------------------------
extern "C" void kernel_launch(void* const* d_in, const int* in_sizes, int n_in,
                              void* d_out, int out_size, void* d_ws, size_t ws_size,
                              hipStream_t stream) {
  const float* u_state = (const float*)d_in[0];  // [8192][64] 0/1 floats
  const float* Wvu     = (const float*)d_in[1];  // [256][64]
  const float* Whu     = (const float*)d_in[2];  // [256][64]
  const float* Whv     = (const float*)d_in[3];  // [256][256]
  const float* bv      = (const float*)d_in[4];  // [256]
  const float* bh      = (const float*)d_in[5];  // [256]
  int* out = (int*)d_out;                        // [8][8192][256] as int32 0/1

  // workspace: WhvT 256KB + uh 8MB + uv 8MB = ~16.8 MB
  float* ws   = (float*)d_ws;
  float* WhvT = ws;                          // 65536 f
  float* uh   = WhvT + NF * NF;              // [8192][256]
  float* uv   = uh + (size_t)BATCH * NF;

  k_transpose<<<NF, NF, 0, stream>>>(Whv, WhvT);
  k_udot<<<BATCH / RTI, NF, 0, stream>>>(u_state, Whu, uh);   // u @ Whu.T
  k_udot<<<BATCH / RTI, NF, 0, stream>>>(u_state, Wvu, uv);   // u @ Wvu.T
  // whole Gibbs chain in ONE launch (row-independent blocks), 8 waves/block
  k_chain<<<BATCH / RPB, TPB, 0, stream>>>(Whv, WhvT, uh, uv, bh, bv, out);

  (void)in_sizes; (void)n_in; (void)out_size; (void)ws_size;
}